// Round 12
// baseline (47.171 us; speedup 1.0000x reference)
//
#include <hip/hip_runtime.h>

#define BATCH 64
#define TLEN  2048
#define DDIM  256
#define ADIM  128
#define TM    16          // t-rows per step
#define STEPS 8           // steps per block
#define EPSC  1e-7f

typedef __bf16 bf16x8 __attribute__((ext_vector_type(8)));
typedef float  f32x4  __attribute__((ext_vector_type(4)));

// DPP-based add of a lane-permuted copy (VALU pipe, not LDS)
template <int CTRL>
__device__ __forceinline__ float dpp_add(float v) {
    int vi = __builtin_bit_cast(int, v);
    int sw = __builtin_amdgcn_update_dpp(vi, vi, CTRL, 0xF, 0xF, false);
    return v + __builtin_bit_cast(float, sw);
}

// raw workgroup barrier: orders LDS only, leaves DMA (vmcnt) in flight
__device__ __forceinline__ void bar_lds() {
    asm volatile("s_waitcnt lgkmcnt(0)" ::: "memory");
    __builtin_amdgcn_s_barrier();
}

// async global->LDS DMA, 16B/lane; dst must be wave-uniform (HW adds lane*16)
__device__ __forceinline__ void gload_lds16(const void* g, void* l) {
    __builtin_amdgcn_global_load_lds(
        (const __attribute__((address_space(1))) void*)g,
        (__attribute__((address_space(3))) void*)l, 16, 0, 0);
}

// ws layout:
//   [0,      65536)  : Wf  bf16[32768]  (B-fragment-ordered W)
//   [65536, 131072)  : N   f32[16384]   (unnormalized numerator, per b,d)
//   [131072,131328)  : s   f32[64]      (unnormalized denominator, per b)

__global__ __launch_bounds__(256) void prep_kernel(const float* __restrict__ W,
                                                   __bf16* __restrict__ Wf,
                                                   float* __restrict__ N,
                                                   float* __restrict__ s) {
    int idx = blockIdx.x * 256 + threadIdx.x;   // [0, 32768)
    int j  = idx & 7;
    int l  = (idx >> 3) & 63;
    int nt = (idx >> 9) & 7;
    int kt = idx >> 12;
    int k = kt * 32 + (l >> 4) * 8 + j;         // K index into D
    int n = nt * 16 + (l & 15);                 // N index into A
    Wf[idx] = (__bf16)W[k * ADIM + n];
    if (idx < BATCH * DDIM) N[idx] = 0.0f;
    if (idx >= BATCH * DDIM && idx < BATCH * DDIM + BATCH) s[idx - BATCH * DDIM] = 0.0f;
}

// Thin persistent kernel: 16-row steps, x via global_load_lds (f32, src-swizzled),
// W in registers (col-split per wave), 4 blocks/CU => 16 waves/CU.
__global__ __launch_bounds__(256, 4) void attn_main(const float* __restrict__ x,
                                                    const float* __restrict__ bias,
                                                    const float* __restrict__ u,
                                                    const __bf16* __restrict__ Wf,
                                                    float* __restrict__ N,
                                                    float* __restrict__ s) {
    __shared__ char  xs[2][TM * DDIM * 4];   // 2 x 16 KB f32, phys-linear/src-swizzled
    __shared__ float wpart[4][TM];           // per-wave 32-col row partials
    __shared__ float wlds[TM];               // exp(z) per row of current step

    const int b    = blockIdx.x >> 4;            // 16 blocks per batch
    const int t00  = (blockIdx.x & 15) * (STEPS * TM);
    const int tid  = threadIdx.x;
    const int wave = tid >> 6;
    const int lane = tid & 63;
    const int lm   = lane & 15;                  // C col-within-16 / A-frag row
    const int lk   = lane >> 4;                  // A-frag k-block / C row-quad

    // wave w owns A-columns [w*32, w*32+32)
    float bias_r[2], u_r[2];
#pragma unroll
    for (int ntl = 0; ntl < 2; ++ntl) {
        bias_r[ntl] = bias[wave * 32 + ntl * 16 + lm];
        u_r[ntl]    = u[wave * 32 + ntl * 16 + lm];
    }

    // W fragments for this wave's 2 n-tiles (32 VGPRs), coalesced b128 loads
    bf16x8 wfreg[8][2];
#pragma unroll
    for (int kt = 0; kt < 8; ++kt)
#pragma unroll
        for (int ntl = 0; ntl < 2; ++ntl)
            wfreg[kt][ntl] = *(const bf16x8*)(Wf + ((size_t)((kt * 8 + wave * 2 + ntl) * 64 + lane)) * 8);

    float accd = 0.f;   // pooling accumulator: this thread owns column d = tid
    float sreg = 0.f;   // denominator partial (threads tid<16 only)

    // DMA geometry: round r of wave w stages row (r*4 + wave); source swizzled.
    const char* xtile = (const char*)(x + (size_t)(b * TLEN + t00) * DDIM);

    // ---- prologue: DMA step 0 into xs[0] ----
#pragma unroll
    for (int r = 0; r < 4; ++r) {
        const int  row  = r * 4 + wave;
        const unsigned sc = ((unsigned)(lane * 16)) ^ (unsigned)((row & 7) << 4);
        gload_lds16(xtile + (size_t)row * 1024 + sc,
                    (char*)xs[0] + r * 4096 + wave * 1024);
    }

    for (int it = 0; it < STEPS; ++it) {
        const char* buf = xs[it & 1];
        __syncthreads();   // drains vmcnt: step-it tile resident; orders prev reads

        // ---- issue DMA for step it+1 (in flight across this whole step) ----
        if (it + 1 < STEPS) {
            const char* xn = xtile + (size_t)(it + 1) * TM * DDIM * 4;
            char* dst = (char*)xs[(it + 1) & 1];
#pragma unroll
            for (int r = 0; r < 4; ++r) {
                const int  row  = r * 4 + wave;
                const unsigned sc = ((unsigned)(lane * 16)) ^ (unsigned)((row & 7) << 4);
                gload_lds16(xn + (size_t)row * 1024 + sc,
                            dst + r * 4096 + wave * 1024);
            }
        }

        // ---- GEMM: 16 rows x 32 cols per wave; f32 frags from LDS, cvt bf16 ----
        f32x4 acc[2];
        acc[0] = (f32x4){0.f, 0.f, 0.f, 0.f};
        acc[1] = (f32x4){0.f, 0.f, 0.f, 0.f};
#pragma unroll
        for (int kt = 0; kt < 8; ++kt) {
            const unsigned msk  = (unsigned)((lm & 7) << 4);
            const unsigned base = (unsigned)(kt * 128 + lk * 32);
            const char* rowp = buf + lm * 1024;
            f32x4 lo = *(const f32x4*)(rowp + (base ^ msk));
            f32x4 hi = *(const f32x4*)(rowp + ((base + 16u) ^ msk));
            bf16x8 a;
#pragma unroll
            for (int i = 0; i < 4; ++i) { a[i] = (__bf16)lo[i]; a[4 + i] = (__bf16)hi[i]; }
            acc[0] = __builtin_amdgcn_mfma_f32_16x16x32_bf16(a, wfreg[kt][0], acc[0], 0, 0, 0);
            acc[1] = __builtin_amdgcn_mfma_f32_16x16x32_bf16(a, wfreg[kt][1], acc[1], 0, 0, 0);
        }

        // ---- logits: tanh-dot-u, 16-lane DPP reduce -> wpart[wave][t] ----
#pragma unroll
        for (int reg = 0; reg < 4; ++reg) {
            float p = 0.f;
#pragma unroll
            for (int ntl = 0; ntl < 2; ++ntl) {
                float lg = acc[ntl][reg] + bias_r[ntl];
                float e  = __expf(2.0f * lg);
                float th = 1.0f - 2.0f * __builtin_amdgcn_rcpf(e + 1.0f);  // tanh, inf-safe
                p += th * u_r[ntl];
            }
            p = dpp_add<0xB1>(p);   // xor 1
            p = dpp_add<0x4E>(p);   // xor 2
            p = dpp_add<0x141>(p);  // row_half_mirror
            p = dpp_add<0x140>(p);  // row_mirror -> full 16-lane sum
            if (lm == 0) wpart[wave][lk * 4 + reg] = p;
        }
        bar_lds();

        // ---- combine wave partials, exp (16 threads), denominator in regs ----
        if (tid < TM) {
            float z  = wpart[0][tid] + wpart[1][tid] + wpart[2][tid] + wpart[3][tid];
            float wv = __expf(z);
            wlds[tid] = wv;
            sreg += wv;
        }
        bar_lds();

        // ---- pooling: thread owns column d = tid; 16 f32 rows ----
#pragma unroll
        for (int t = 0; t < TM; ++t) {
            float xv = *(const float*)(buf + t * 1024 + (((unsigned)(tid * 4)) ^ (unsigned)((t & 7) << 4)));
            accd += xv * wlds[t];
        }
        // next iteration's __syncthreads orders these reads vs the step+2 DMA
    }

    // ---- epilogue ----
    if (tid < TM) {
        float ss = sreg;
#pragma unroll
        for (int off = 1; off < 16; off <<= 1) ss += __shfl_xor(ss, off);
        if (tid == 0) atomicAdd(&s[b], ss);
    }
    atomicAdd(&N[b * DDIM + tid], accd);
}

__global__ __launch_bounds__(256) void finalize_kernel(const float* __restrict__ N,
                                                       const float* __restrict__ s,
                                                       float* __restrict__ out) {
    int idx = blockIdx.x * 256 + threadIdx.x;   // [0, 16384)
    out[idx] = N[idx] / (s[idx >> 8] + EPSC);
}

extern "C" void kernel_launch(void* const* d_in, const int* in_sizes, int n_in,
                              void* d_out, int out_size, void* d_ws, size_t ws_size,
                              hipStream_t stream) {
    const float* x    = (const float*)d_in[0];
    const float* W    = (const float*)d_in[1];
    const float* bias = (const float*)d_in[2];
    const float* u    = (const float*)d_in[3];
    float* out = (float*)d_out;

    char* ws = (char*)d_ws;
    __bf16* Wf = (__bf16*)ws;
    float*  N  = (float*)(ws + 65536);
    float*  s  = (float*)(ws + 131072);

    prep_kernel<<<128, 256, 0, stream>>>(W, Wf, N, s);
    attn_main<<<BATCH * TLEN / (STEPS * TM), 256, 0, stream>>>(x, bias, u, Wf, N, s);
    finalize_kernel<<<(BATCH * DDIM) / 256, 256, 0, stream>>>(N, s, out);
}

// Round 13
// 38.380 us; speedup vs baseline: 1.2290x; 1.2290x over previous
//
#include <hip/hip_runtime.h>

#define BATCH 64
#define TLEN  2048
#define DDIM  256
#define ADIM  128
#define TM    64          // t-rows per tile
#define TILES 4           // tiles per block
#define NBLK  (BATCH * TLEN / (TILES * TM))   // 512 blocks, 8 per batch
#define EPSC  1e-7f

typedef __bf16 bf16x8 __attribute__((ext_vector_type(8)));
typedef float  f32x4  __attribute__((ext_vector_type(4)));

// DPP-based add of a lane-permuted copy (VALU pipe, not LDS)
template <int CTRL>
__device__ __forceinline__ float dpp_add(float v) {
    int vi = __builtin_bit_cast(int, v);
    int sw = __builtin_amdgcn_update_dpp(vi, vi, CTRL, 0xF, 0xF, false);
    return v + __builtin_bit_cast(float, sw);
}

// raw workgroup barrier: orders LDS only, leaves global loads (vmcnt) in flight
__device__ __forceinline__ void bar_lds() {
    asm volatile("s_waitcnt lgkmcnt(0)" ::: "memory");
    __builtin_amdgcn_s_barrier();
}

// ws layout:
//   [0,      524288) : Npart f32[512][256]  (per-block numerator partials)
//   [524288, 526336) : spart f32[512]       (per-block denominator partials)
// pure overwrite -> no zero-init needed.

__global__ __launch_bounds__(256, 2) void attn_main(const float* __restrict__ x,
                                                    const float* __restrict__ W,
                                                    const float* __restrict__ bias,
                                                    const float* __restrict__ u,
                                                    float* __restrict__ Npart,
                                                    float* __restrict__ spart) {
    __shared__ char  xs[TM * DDIM * 2];      // 32 KB single buffer, XOR-swizzled
    __shared__ float wpart[4][TM];           // per-wave 32-col row partials (1 KB)
    __shared__ float fpart[4][32][8];        // pooling partials (4 KB)
    __shared__ float ssum_lds[4];

    const int bid  = blockIdx.x;
    const int b    = bid >> 3;                   // 8 blocks per batch
    const int t00  = (bid & 7) * (TILES * TM);
    const int tid  = threadIdx.x;
    const int wave = tid >> 6;
    const int lane = tid & 63;
    const int lm   = lane & 15;                  // col index within 16x16 C tile
    const int lk   = lane >> 4;                  // k-block / row-quad index
    const int row  = wave * 16 + lm;             // local row this thread stages

    const float* xbase = x + ((size_t)(b * TLEN + t00 + row)) * DDIM;

    // ---- prologue A: issue tile-0 x loads FIRST (longest latency) ----
    f32x4 fa[8], fb[8];
#pragma unroll
    for (int kt = 0; kt < 8; ++kt) {
        fa[kt] = *(const f32x4*)(xbase + kt * 32 + lk * 8);
        fb[kt] = *(const f32x4*)(xbase + kt * 32 + lk * 8 + 4);
    }

    // ---- prologue B: W fragments direct from global (L2-hot, coalesced-16) ----
    // wave w owns A-columns [w*32, w*32+32); frag elem j <-> k = kt*32+lk*8+j
    bf16x8 wfreg[8][2];
#pragma unroll
    for (int kt = 0; kt < 8; ++kt)
#pragma unroll
        for (int ntl = 0; ntl < 2; ++ntl) {
            const float* wp = W + (size_t)(kt * 32 + lk * 8) * ADIM + wave * 32 + ntl * 16 + lm;
            bf16x8 w;
#pragma unroll
            for (int j = 0; j < 8; ++j) w[j] = (__bf16)wp[j * ADIM];
            wfreg[kt][ntl] = w;
        }

    float bias_r[2], u_r[2];
#pragma unroll
    for (int ntl = 0; ntl < 2; ++ntl) {
        bias_r[ntl] = bias[wave * 32 + ntl * 16 + lm];
        u_r[ntl]    = u[wave * 32 + ntl * 16 + lm];
    }

    float vacc[8] = {0.f, 0.f, 0.f, 0.f, 0.f, 0.f, 0.f, 0.f};
    float sreg = 0.f;                   // per-thread denominator partial (x32 overcount)
    const int dgrp = tid & 31;          // pooling: d = dgrp*8 + j
    const int tgrp = tid >> 5;          // pooling: t = tgrp*8 + i

    for (int it = 0; it < TILES; ++it) {
        // ---- phase 1: cvt + stash current tile; then issue next tile's loads ----
#pragma unroll
        for (int kt = 0; kt < 8; ++kt) {
            bf16x8 a;
#pragma unroll
            for (int i = 0; i < 4; ++i) { a[i] = (__bf16)fa[kt][i]; a[4 + i] = (__bf16)fb[kt][i]; }
            *(bf16x8*)(xs + ((row * 512 + (kt * 32 + lk * 8) * 2) ^ ((row & 7) << 4))) = a;
        }
        if (it + 1 < TILES) {
            const float* xn = xbase + (size_t)(it + 1) * TM * DDIM;
#pragma unroll
            for (int kt = 0; kt < 8; ++kt) {
                fa[kt] = *(const f32x4*)(xn + kt * 32 + lk * 8);
                fb[kt] = *(const f32x4*)(xn + kt * 32 + lk * 8 + 4);
            }
        }
        bar_lds();   // stash visible; prefetch stays in flight (no vmcnt drain)

        // ---- phase 2: GEMM (A from LDS, W from regs) + logits -> wpart ----
        f32x4 acc[4][2];
#pragma unroll
        for (int m = 0; m < 4; ++m)
#pragma unroll
            for (int ntl = 0; ntl < 2; ++ntl) acc[m][ntl] = (f32x4){0.f, 0.f, 0.f, 0.f};

#pragma unroll
        for (int kt = 0; kt < 8; ++kt) {
#pragma unroll
            for (int m = 0; m < 4; ++m) {
                const int r = m * 16 + lm;
                bf16x8 afrag = *(const bf16x8*)(xs + ((r * 512 + (kt * 32 + lk * 8) * 2) ^ ((r & 7) << 4)));
                acc[m][0] = __builtin_amdgcn_mfma_f32_16x16x32_bf16(afrag, wfreg[kt][0], acc[m][0], 0, 0, 0);
                acc[m][1] = __builtin_amdgcn_mfma_f32_16x16x32_bf16(afrag, wfreg[kt][1], acc[m][1], 0, 0, 0);
            }
        }

#pragma unroll
        for (int m = 0; m < 4; ++m) {
#pragma unroll
            for (int reg = 0; reg < 4; ++reg) {
                float p = 0.f;
#pragma unroll
                for (int ntl = 0; ntl < 2; ++ntl) {
                    float lg = acc[m][ntl][reg] + bias_r[ntl];
                    float e  = __expf(2.0f * lg);
                    float th = 1.0f - 2.0f * __builtin_amdgcn_rcpf(e + 1.0f);  // tanh, inf-safe
                    p += th * u_r[ntl];
                }
                p = dpp_add<0xB1>(p);   // xor 1
                p = dpp_add<0x4E>(p);   // xor 2
                p = dpp_add<0x141>(p);  // row_half_mirror
                p = dpp_add<0x140>(p);  // row_mirror -> full 16-lane sum
                if (lm == 0) wpart[wave][m * 16 + lk * 4 + reg] = p;
            }
        }
        bar_lds();

        // ---- phase 3: every thread computes z/exp for its 8 rows, then pools ----
        f32x4 zlo = (f32x4){0.f, 0.f, 0.f, 0.f}, zhi = (f32x4){0.f, 0.f, 0.f, 0.f};
#pragma unroll
        for (int w = 0; w < 4; ++w) {
            zlo += *(const f32x4*)&wpart[w][tgrp * 8];
            zhi += *(const f32x4*)&wpart[w][tgrp * 8 + 4];
        }
        float wv[8];
#pragma unroll
        for (int i = 0; i < 4; ++i) { wv[i] = __expf(zlo[i]); wv[4 + i] = __expf(zhi[i]); }
#pragma unroll
        for (int i = 0; i < 8; ++i) sreg += wv[i];

#pragma unroll
        for (int i = 0; i < 8; ++i) {
            const int t = tgrp * 8 + i;
            bf16x8 xv = *(const bf16x8*)(xs + ((t * 512 + dgrp * 16) ^ ((t & 7) << 4)));
#pragma unroll
            for (int j = 0; j < 8; ++j) vacc[j] += (float)xv[j] * wv[i];
        }
        bar_lds();   // xs / wpart free for next tile
    }

    // ---- epilogue: denominator (each row counted 32x across dgrp) ----
    float ss = sreg;
#pragma unroll
    for (int off = 1; off < 64; off <<= 1) ss += __shfl_xor(ss, off);
    if (lane == 0) ssum_lds[wave] = ss;

    // ---- epilogue: numerator ----
#pragma unroll
    for (int j = 0; j < 8; ++j) vacc[j] += __shfl_xor(vacc[j], 32);
    if (lane < 32) {
        *(f32x4*)&fpart[wave][dgrp][0] = (f32x4){vacc[0], vacc[1], vacc[2], vacc[3]};
        *(f32x4*)&fpart[wave][dgrp][4] = (f32x4){vacc[4], vacc[5], vacc[6], vacc[7]};
    }
    __syncthreads();
    if (tid == 0)
        spart[bid] = (ssum_lds[0] + ssum_lds[1] + ssum_lds[2] + ssum_lds[3]) * (1.0f / 32.0f);
    Npart[(size_t)bid * DDIM + tid] =
          fpart[0][tid >> 3][tid & 7] + fpart[1][tid >> 3][tid & 7]
        + fpart[2][tid >> 3][tid & 7] + fpart[3][tid >> 3][tid & 7];
}

__global__ __launch_bounds__(256) void finalize_kernel(const float* __restrict__ Npart,
                                                       const float* __restrict__ spart,
                                                       float* __restrict__ out) {
    const int b = blockIdx.x;       // one block per batch
    const int d = threadIdx.x;
    float sb = 0.f;
#pragma unroll
    for (int i = 0; i < 8; ++i) sb += spart[b * 8 + i];
    float r = 0.f;
#pragma unroll
    for (int i = 0; i < 8; ++i) r += Npart[(size_t)(b * 8 + i) * DDIM + d];
    out[b * DDIM + d] = r / (sb + EPSC);
}

extern "C" void kernel_launch(void* const* d_in, const int* in_sizes, int n_in,
                              void* d_out, int out_size, void* d_ws, size_t ws_size,
                              hipStream_t stream) {
    const float* x    = (const float*)d_in[0];
    const float* W    = (const float*)d_in[1];
    const float* bias = (const float*)d_in[2];
    const float* u    = (const float*)d_in[3];
    float* out = (float*)d_out;

    char* ws = (char*)d_ws;
    float* Npart = (float*)ws;
    float* spart = (float*)(ws + 524288);

    attn_main<<<NBLK, 256, 0, stream>>>(x, W, bias, u, Npart, spart);
    finalize_kernel<<<BATCH, 256, 0, stream>>>(Npart, spart, out);
}

// Round 14
// 36.892 us; speedup vs baseline: 1.2786x; 1.0403x over previous
//
#include <hip/hip_runtime.h>

#define BATCH 64
#define TLEN  2048
#define DDIM  256
#define ADIM  128
#define TM    64          // t-rows per tile
#define TILES 4           // tiles per block
#define NBLK  (BATCH * TLEN / (TILES * TM))   // 512 blocks, 8 per batch
#define EPSC  1e-7f

typedef __bf16 bf16x8 __attribute__((ext_vector_type(8)));
typedef __bf16 bf16x4 __attribute__((ext_vector_type(4)));
typedef float  f32x4  __attribute__((ext_vector_type(4)));

// DPP-based add of a lane-permuted copy (VALU pipe, not LDS)
template <int CTRL>
__device__ __forceinline__ float dpp_add(float v) {
    int vi = __builtin_bit_cast(int, v);
    int sw = __builtin_amdgcn_update_dpp(vi, vi, CTRL, 0xF, 0xF, false);
    return v + __builtin_bit_cast(float, sw);
}

// raw workgroup barrier: orders LDS only, leaves global loads (vmcnt) in flight
__device__ __forceinline__ void bar_lds() {
    asm volatile("s_waitcnt lgkmcnt(0)" ::: "memory");
    __builtin_amdgcn_s_barrier();
}

// ws layout:
//   [0,      524288) : Npart f32[512][256]  (per-block numerator partials)
//   [524288, 526336) : spart f32[512]       (per-block denominator partials)
// pure overwrite -> no zero-init needed.

__global__ __launch_bounds__(256, 2) void attn_main(const float* __restrict__ x,
                                                    const float* __restrict__ W,
                                                    const float* __restrict__ bias,
                                                    const float* __restrict__ u,
                                                    float* __restrict__ Npart,
                                                    float* __restrict__ spart) {
    __shared__ char  xs[TM * DDIM * 2];      // 32 KB bf16 row-major (512 B/row), XOR-swizzled
    __shared__ float wpart[4][TM];           // per-wave 32-col row partials (1 KB)
    __shared__ float fpart[4][32][8];        // pooling partials (4 KB)
    __shared__ float ssum_lds[4];

    const int bid  = blockIdx.x;
    const int b    = bid >> 3;                   // 8 blocks per batch
    const int t00  = (bid & 7) * (TILES * TM);
    const int tid  = threadIdx.x;
    const int wave = tid >> 6;
    const int lane = tid & 63;
    const int lm   = lane & 15;                  // col index within 16x16 C tile
    const int lk   = lane >> 4;                  // k-block / row-quad index

    // wave-cooperative row loads: wave w owns rows [w*16, w*16+16)
    const float* xw = x + ((size_t)(b * TLEN + t00) + wave * 16) * DDIM;

    // ---- prologue A: issue tile-0 x loads FIRST (1 KB contiguous per instr) ----
    f32x4 fa[16];
#pragma unroll
    for (int i = 0; i < 16; ++i)
        fa[i] = *(const f32x4*)(xw + i * DDIM + lane * 4);

    // ---- prologue B: W fragments direct from global (L2-hot, coalesced-16) ----
    // wave w owns A-columns [w*32, w*32+32); frag elem j <-> k = kt*32+lk*8+j
    bf16x8 wfreg[8][2];
#pragma unroll
    for (int kt = 0; kt < 8; ++kt)
#pragma unroll
        for (int ntl = 0; ntl < 2; ++ntl) {
            const float* wp = W + (size_t)(kt * 32 + lk * 8) * ADIM + wave * 32 + ntl * 16 + lm;
            bf16x8 w;
#pragma unroll
            for (int j = 0; j < 8; ++j) w[j] = (__bf16)wp[j * ADIM];
            wfreg[kt][ntl] = w;
        }

    float bias_r[2], u_r[2];
#pragma unroll
    for (int ntl = 0; ntl < 2; ++ntl) {
        bias_r[ntl] = bias[wave * 32 + ntl * 16 + lm];
        u_r[ntl]    = u[wave * 32 + ntl * 16 + lm];
    }

    float vacc[8] = {0.f, 0.f, 0.f, 0.f, 0.f, 0.f, 0.f, 0.f};
    float sreg = 0.f;                   // per-thread denominator partial (x32 overcount)
    const int dgrp = tid & 31;          // pooling: d = dgrp*8 + j
    const int tgrp = tid >> 5;          // pooling: t = tgrp*8 + i

    for (int it = 0; it < TILES; ++it) {
        // ---- phase 1: cvt + stash current tile (row-contiguous b64 writes) ----
#pragma unroll
        for (int i = 0; i < 16; ++i) {
            const int row = wave * 16 + i;      // row & 7 == i & 7 (wave*16 % 8 == 0)
            bf16x4 a;
#pragma unroll
            for (int j = 0; j < 4; ++j) a[j] = (__bf16)fa[i][j];
            *(bf16x4*)(xs + ((row * 512 + lane * 8) ^ ((i & 7) << 4))) = a;
        }
        // ---- issue next tile's loads BEFORE the barrier (full tile in flight) ----
        if (it + 1 < TILES) {
            const float* xn = xw + (size_t)(it + 1) * TM * DDIM;
#pragma unroll
            for (int i = 0; i < 16; ++i)
                fa[i] = *(const f32x4*)(xn + i * DDIM + lane * 4);
        }
        bar_lds();   // stash visible; prefetch stays in flight (no vmcnt drain)

        // ---- phase 2: GEMM (A from LDS, W from regs) + logits -> wpart ----
        f32x4 acc[4][2];
#pragma unroll
        for (int m = 0; m < 4; ++m)
#pragma unroll
            for (int ntl = 0; ntl < 2; ++ntl) acc[m][ntl] = (f32x4){0.f, 0.f, 0.f, 0.f};

#pragma unroll
        for (int kt = 0; kt < 8; ++kt) {
#pragma unroll
            for (int m = 0; m < 4; ++m) {
                const int r = m * 16 + lm;
                bf16x8 afrag = *(const bf16x8*)(xs + ((r * 512 + kt * 64 + lk * 16) ^ ((r & 7) << 4)));
                acc[m][0] = __builtin_amdgcn_mfma_f32_16x16x32_bf16(afrag, wfreg[kt][0], acc[m][0], 0, 0, 0);
                acc[m][1] = __builtin_amdgcn_mfma_f32_16x16x32_bf16(afrag, wfreg[kt][1], acc[m][1], 0, 0, 0);
            }
        }

#pragma unroll
        for (int m = 0; m < 4; ++m) {
#pragma unroll
            for (int reg = 0; reg < 4; ++reg) {
                float p = 0.f;
#pragma unroll
                for (int ntl = 0; ntl < 2; ++ntl) {
                    float lg = acc[m][ntl][reg] + bias_r[ntl];
                    float e  = __expf(2.0f * lg);
                    float th = 1.0f - 2.0f * __builtin_amdgcn_rcpf(e + 1.0f);  // tanh, inf-safe
                    p += th * u_r[ntl];
                }
                p = dpp_add<0xB1>(p);   // xor 1
                p = dpp_add<0x4E>(p);   // xor 2
                p = dpp_add<0x141>(p);  // row_half_mirror
                p = dpp_add<0x140>(p);  // row_mirror -> full 16-lane sum
                if (lm == 0) wpart[wave][m * 16 + lk * 4 + reg] = p;
            }
        }
        bar_lds();

        // ---- phase 3: every thread computes z/exp for its 8 rows, then pools ----
        f32x4 zlo = (f32x4){0.f, 0.f, 0.f, 0.f}, zhi = (f32x4){0.f, 0.f, 0.f, 0.f};
#pragma unroll
        for (int w = 0; w < 4; ++w) {
            zlo += *(const f32x4*)&wpart[w][tgrp * 8];
            zhi += *(const f32x4*)&wpart[w][tgrp * 8 + 4];
        }
        float wv[8];
#pragma unroll
        for (int i = 0; i < 4; ++i) { wv[i] = __expf(zlo[i]); wv[4 + i] = __expf(zhi[i]); }
#pragma unroll
        for (int i = 0; i < 8; ++i) sreg += wv[i];

#pragma unroll
        for (int i = 0; i < 8; ++i) {
            const int t = tgrp * 8 + i;
            bf16x8 xv = *(const bf16x8*)(xs + ((t * 512 + dgrp * 16) ^ ((t & 7) << 4)));
#pragma unroll
            for (int j = 0; j < 8; ++j) vacc[j] += (float)xv[j] * wv[i];
        }
        bar_lds();   // xs / wpart free for next tile
    }

    // ---- epilogue: denominator (each row counted 32x across dgrp) ----
    float ss = sreg;
#pragma unroll
    for (int off = 1; off < 64; off <<= 1) ss += __shfl_xor(ss, off);
    if (lane == 0) ssum_lds[wave] = ss;

    // ---- epilogue: numerator ----
#pragma unroll
    for (int j = 0; j < 8; ++j) vacc[j] += __shfl_xor(vacc[j], 32);
    if (lane < 32) {
        *(f32x4*)&fpart[wave][dgrp][0] = (f32x4){vacc[0], vacc[1], vacc[2], vacc[3]};
        *(f32x4*)&fpart[wave][dgrp][4] = (f32x4){vacc[4], vacc[5], vacc[6], vacc[7]};
    }
    __syncthreads();
    if (tid == 0)
        spart[bid] = (ssum_lds[0] + ssum_lds[1] + ssum_lds[2] + ssum_lds[3]) * (1.0f / 32.0f);
    Npart[(size_t)bid * DDIM + tid] =
          fpart[0][tid >> 3][tid & 7] + fpart[1][tid >> 3][tid & 7]
        + fpart[2][tid >> 3][tid & 7] + fpart[3][tid >> 3][tid & 7];
}

__global__ __launch_bounds__(256) void finalize_kernel(const float* __restrict__ Npart,
                                                       const float* __restrict__ spart,
                                                       float* __restrict__ out) {
    const int b = blockIdx.x;       // one block per batch
    const int d = threadIdx.x;
    float sb = 0.f;
#pragma unroll
    for (int i = 0; i < 8; ++i) sb += spart[b * 8 + i];
    float r = 0.f;
#pragma unroll
    for (int i = 0; i < 8; ++i) r += Npart[(size_t)(b * 8 + i) * DDIM + d];
    out[b * DDIM + d] = r / (sb + EPSC);
}

extern "C" void kernel_launch(void* const* d_in, const int* in_sizes, int n_in,
                              void* d_out, int out_size, void* d_ws, size_t ws_size,
                              hipStream_t stream) {
    const float* x    = (const float*)d_in[0];
    const float* W    = (const float*)d_in[1];
    const float* bias = (const float*)d_in[2];
    const float* u    = (const float*)d_in[3];
    float* out = (float*)d_out;

    char* ws = (char*)d_ws;
    float* Npart = (float*)ws;
    float* spart = (float*)(ws + 524288);

    attn_main<<<NBLK, 256, 0, stream>>>(x, W, bias, u, Npart, spart);
    finalize_kernel<<<BATCH, 256, 0, stream>>>(Npart, spart, out);
}